// Round 12
// baseline (660.408 us; speedup 1.0000x reference)
//
#include <hip/hip_runtime.h>
#include <hip/hip_cooperative_groups.h>
#include <math.h>

namespace cg = cooperative_groups;

#define BB 16
#define LL 200
#define HH 128
#define DD 64
#define NQT 25          // 200/8 q-tiles
#define NEGF -4294967295.0f
#define SQRTH 11.313708498984761f

struct Params {
    const int* log_seqs; const int* tm; const int* pos_seqs; const int* neg_seqs;
    const float* item_emb; const float* posK; const float* posV;
    const float* timeK; const float* timeV;
    const float* Wq; const float* bq; const float* Wk; const float* bk;
    const float* Wv; const float* bv;
    const float* ln1_g; const float* ln1_b;
    const float* W1; const float* b1; const float* W2; const float* b2;
    const float* ln2_g; const float* ln2_b;
    const float* lnf_g; const float* lnf_b;
    float* seqs; float* Q; float* Kp; float* Vp; float* AO; float* projK;
    float* out;
};

// ---- phase: QKV projection, 8 rows/tile, 400 tiles (layer 0 embeds) ----
__device__ void ph_qkv(const Params& P, float* smem, int tile, int layer) {
    float (*s_lds)[HH] = (float (*)[HH])smem;
    int r0g = tile * 8;
    int t = threadIdx.x;
    __syncthreads();                       // LDS reuse guard (stride iterations)
    if (layer == 0) {
        int r = t >> 5, d4 = t & 31;       // 8 rows x 32 float4
        int id = P.log_seqs[r0g + r];
        float4 v = make_float4(0.f, 0.f, 0.f, 0.f);
        if (id != 0) {
            v = ((const float4*)(P.item_emb + id * HH))[d4];
            v.x *= SQRTH; v.y *= SQRTH; v.z *= SQRTH; v.w *= SQRTH;
        }
        *(float4*)&s_lds[r][d4 * 4] = v;
        ((float4*)(P.seqs + r0g * HH))[t] = v;
    } else {
        ((float4*)s_lds)[t] = ((const float4*)(P.seqs + r0g * HH))[t];
    }
    __syncthreads();
    const float* Wq = P.Wq + layer * HH * HH; const float* bq = P.bq + layer * HH;
    const float* Wk = P.Wk + layer * HH * HH; const float* bk = P.bk + layer * HH;
    const float* Wv = P.Wv + layer * HH * HH; const float* bv = P.bv + layer * HH;
    int c = t & 127, rg = t >> 7;
    float aq[4] = {0.f, 0.f, 0.f, 0.f};
    float ak[4] = {0.f, 0.f, 0.f, 0.f};
    float av[4] = {0.f, 0.f, 0.f, 0.f};
    const float4* wq4 = (const float4*)(Wq + c * HH);
    const float4* wk4 = (const float4*)(Wk + c * HH);
    const float4* wv4 = (const float4*)(Wv + c * HH);
#pragma unroll 4
    for (int k4 = 0; k4 < HH / 4; ++k4) {
        float4 wq = wq4[k4], wk = wk4[k4], wv = wv4[k4];
#pragma unroll
        for (int r = 0; r < 4; ++r) {
            float4 s = *(const float4*)&s_lds[rg * 4 + r][k4 * 4];
            aq[r] += s.x * wq.x + s.y * wq.y + s.z * wq.z + s.w * wq.w;
            ak[r] += s.x * wk.x + s.y * wk.y + s.z * wk.z + s.w * wk.w;
            av[r] += s.x * wv.x + s.y * wv.y + s.z * wv.z + s.w * wv.w;
        }
    }
#pragma unroll
    for (int r = 0; r < 4; ++r) {
        int row = r0g + rg * 4 + r;
        int l = row % LL;
        P.Q[row * HH + c]  = aq[r] + bq[c];
        P.Kp[row * HH + c] = ak[r] + bk[c] + P.posK[l * HH + c];
        P.Vp[row * HH + c] = av[r] + bv[c] + P.posV[l * HH + c];
    }
}

// ---- phase: projK[bh,q,tt] = Q . timeK[tt], 800 tiles, TK double-buffered ----
__device__ void ph_proj(const Params& P, float* smem, int tile) {
    float (*Qs)[68] = (float (*)[68])smem;                    // 8x68 = 544
    float (*TK)[32][68] = (float (*)[32][68])(smem + 544);    // 2x32x68 = 4352
    int bh = tile / NQT, qt = tile % NQT;
    int b = bh >> 1, h = bh & 1;
    int qlo = qt * 8;
    int t = threadIdx.x;
    __syncthreads();                       // LDS reuse guard
    if (t < 128) {
        int r = t >> 4, d4 = t & 15;
        *(float4*)&Qs[r][d4 * 4] =
            ((const float4*)(P.Q + (b * LL + qlo + r) * HH + h * DD))[d4];
    }
    for (int x = t; x < 512; x += 256) {
        int i = x >> 4, d4 = x & 15;
        *(float4*)&TK[0][i][d4 * 4] =
            ((const float4*)(P.timeK + i * HH + h * DD))[d4];
    }
    int tq = t >> 5, ttl = t & 31;
    for (int ch = 0; ch < 9; ++ch) {
        __syncthreads();
        if (ch + 1 < 9) {
            int nb = (ch + 1) * 32;
            for (int x = t; x < 512; x += 256) {
                int i = x >> 4, d4 = x & 15;
                int tt = nb + i;
                if (tt < 257)
                    *(float4*)&TK[(ch + 1) & 1][i][d4 * 4] =
                        ((const float4*)(P.timeK + tt * HH + h * DD))[d4];
            }
        }
        int tt = ch * 32 + ttl;
        if (tt < 257) {
            float acc = 0.f;
#pragma unroll
            for (int d4 = 0; d4 < 16; ++d4) {
                float4 qv = *(const float4*)&Qs[tq][d4 * 4];
                float4 kv = *(const float4*)&TK[ch & 1][ttl][d4 * 4];
                acc += qv.x * kv.x + qv.y * kv.y + qv.z * kv.z + qv.w * kv.w;
            }
            P.projK[(bh * LL + qlo + tq) * 257 + tt] = acc;
        }
    }
}

// ---- phase: scores + register-softmax + hist + PV, 800 tiles ----
__device__ void ph_attn(const Params& P, float* smem, int* s_allmask_p, int tile) {
    float (*K_s)[68] = (float (*)[68])smem;       // 32x68 = 2176
    float* smemW = smem + 2176;                   // 457*12 = 5484
#define WT(i, j) smemW[(i) * 12 + (j)]
    int bh = tile / NQT, qt = tile % NQT;
    int b = bh >> 1, h = bh & 1;
    int qlo = qt * 8;
    int t = threadIdx.x;
    int tq = t >> 5, lane = t & 31, g = tq;
    int q = qlo + tq;
    int qhi = qlo + 7;
    __syncthreads();                       // LDS reuse guard
    if (t == 0) *s_allmask_p = 0;
    for (int x = 200 * 12 + t; x < 457 * 12; x += 256) smemW[x] = 0.f;
    float4 qreg[16];
    {
        const float4* qp = (const float4*)(P.Q + (b * LL + q) * HH + h * DD);
#pragma unroll
        for (int d4 = 0; d4 < 16; ++d4) qreg[d4] = qp[d4];
    }
    const int* tmrow = P.tm + (b * LL + q) * LL;
    const float* projrow = P.projK + (bh * LL + q) * 257;
    const int* lsrow = P.log_seqs + b * LL;

    // scores into registers s[7]
    float s[7];
#pragma unroll
    for (int j = 0; j < 7; ++j) s[j] = NEGF;
    int nkc = (qhi >> 5) + 1;              // block-uniform, 1..7
#pragma unroll
    for (int kc = 0; kc < 7; ++kc) {
        if (kc < nkc) {
            int kbase = kc * 32;
            for (int x = t; x < 512; x += 256) {
                int i = x >> 4, d4 = x & 15;
                int k = kbase + i;
                if (k < LL)
                    *(float4*)&K_s[i][d4 * 4] =
                        ((const float4*)(P.Kp + (b * LL + k) * HH + h * DD))[d4];
            }
            __syncthreads();
            int k = kbase + lane;
            if (k <= q && lsrow[k] != 0) {
                float acc = 0.f;
#pragma unroll
                for (int d4 = 0; d4 < 16; ++d4) {
                    float4 kv = *(const float4*)&K_s[lane][d4 * 4];
                    acc += qreg[d4].x * kv.x + qreg[d4].y * kv.y +
                           qreg[d4].z * kv.z + qreg[d4].w * kv.w;
                }
                s[kc] = (acc + projrow[tmrow[k]]) * 0.125f;
            }
            __syncthreads();
        }
    }

    // softmax fully in registers (32 lanes per q row)
    float mx = s[0];
#pragma unroll
    for (int j = 1; j < 7; ++j) mx = fmaxf(mx, s[j]);
    mx = fmaxf(mx, __shfl_xor(mx, 1, 64));
    mx = fmaxf(mx, __shfl_xor(mx, 2, 64));
    mx = fmaxf(mx, __shfl_xor(mx, 4, 64));
    mx = fmaxf(mx, __shfl_xor(mx, 8, 64));
    mx = fmaxf(mx, __shfl_xor(mx, 16, 64));
    bool allmask = (mx == NEGF);           // exp(0)=1 per k -> uniform 1/200 (matches ref)
    float sum = 0.f;
#pragma unroll
    for (int j = 0; j < 7; ++j) {
        int k = lane + 32 * j;
        float e = (k < LL) ? __expf(s[j] - mx) : 0.f;
        s[j] = e;
        sum += e;
    }
    sum += __shfl_xor(sum, 1, 64);
    sum += __shfl_xor(sum, 2, 64);
    sum += __shfl_xor(sum, 4, 64);
    sum += __shfl_xor(sum, 8, 64);
    sum += __shfl_xor(sum, 16, 64);
    float inv = 1.0f / sum;
    int klim = allmask ? LL : (q + 1);
    if (allmask && lane == 0) *s_allmask_p = 1;
#pragma unroll
    for (int j = 0; j < 7; ++j) {
        int k = lane + 32 * j;
        if (k < LL) {
            float p = s[j] * inv;
            WT(k, tq) = p;
            if (k < klim && p != 0.f)
                atomicAdd(&WT(200 + tmrow[k], tq), p);
        }
    }
    __syncthreads();

    // PV: direct coalesced global reads, broadcast LDS weights
    int kmax = (*s_allmask_p) ? LL : (qhi + 1);
    float a00=0.f,a01=0.f,a10=0.f,a11=0.f,a20=0.f,a21=0.f,a30=0.f,a31=0.f;
    float a40=0.f,a41=0.f,a50=0.f,a51=0.f,a60=0.f,a61=0.f,a70=0.f,a71=0.f;
#define PV_STEP(WROW, SRCPTR)                                            \
    {                                                                    \
        const float* wr = &WROW;                                         \
        float4 w0 = *(const float4*)wr;                                  \
        float4 w1 = *(const float4*)(wr + 4);                            \
        float2 vv = *(const float2*)(SRCPTR);                            \
        a00 += w0.x * vv.x; a01 += w0.x * vv.y;                          \
        a10 += w0.y * vv.x; a11 += w0.y * vv.y;                          \
        a20 += w0.z * vv.x; a21 += w0.z * vv.y;                          \
        a30 += w0.w * vv.x; a31 += w0.w * vv.y;                          \
        a40 += w1.x * vv.x; a41 += w1.x * vv.y;                          \
        a50 += w1.y * vv.x; a51 += w1.y * vv.y;                          \
        a60 += w1.z * vv.x; a61 += w1.z * vv.y;                          \
        a70 += w1.w * vv.x; a71 += w1.w * vv.y;                          \
    }
    for (int i = g; i < kmax; i += 8)
        PV_STEP(WT(i, 0), P.Vp + (b * LL + i) * HH + h * DD + lane * 2);
    for (int i = g; i < 257; i += 8)
        PV_STEP(WT(200 + i, 0), P.timeV + i * HH + h * DD + lane * 2);
#undef PV_STEP
    __syncthreads();
    float* part = smemW;
    part[g * 512 + 0 * 64 + lane * 2] = a00; part[g * 512 + 0 * 64 + lane * 2 + 1] = a01;
    part[g * 512 + 1 * 64 + lane * 2] = a10; part[g * 512 + 1 * 64 + lane * 2 + 1] = a11;
    part[g * 512 + 2 * 64 + lane * 2] = a20; part[g * 512 + 2 * 64 + lane * 2 + 1] = a21;
    part[g * 512 + 3 * 64 + lane * 2] = a30; part[g * 512 + 3 * 64 + lane * 2 + 1] = a31;
    part[g * 512 + 4 * 64 + lane * 2] = a40; part[g * 512 + 4 * 64 + lane * 2 + 1] = a41;
    part[g * 512 + 5 * 64 + lane * 2] = a50; part[g * 512 + 5 * 64 + lane * 2 + 1] = a51;
    part[g * 512 + 6 * 64 + lane * 2] = a60; part[g * 512 + 6 * 64 + lane * 2 + 1] = a61;
    part[g * 512 + 7 * 64 + lane * 2] = a70; part[g * 512 + 7 * 64 + lane * 2 + 1] = a71;
    __syncthreads();
    {
        float ox = 0.f, oy = 0.f;
#pragma unroll
        for (int gg = 0; gg < 8; ++gg) {
            ox += part[gg * 512 + tq * 64 + lane * 2];
            oy += part[gg * 512 + tq * 64 + lane * 2 + 1];
        }
        *(float2*)(P.AO + (b * LL + q) * HH + h * DD + lane * 2) =
            make_float2(ox, oy);
    }
#undef WT
}

// ---- phase: LN1 + FFN + LN2 (+ final lnf + logits), 8 rows/tile, 400 tiles ----
__device__ void ph_ffn(const Params& P, float* smem, int tile, int layer) {
    float (*s_lds)[HH] = (float (*)[HH])smem;          // 8x128 = 1024
    float (*h_lds)[HH] = (float (*)[HH])(smem + 1024); // 8x128 = 1024
    int r0g = tile * 8;
    int t = threadIdx.x;
    int do_final = (layer == 1);
    const float* g1  = P.ln1_g + layer * HH; const float* be1 = P.ln1_b + layer * HH;
    const float* W1  = P.W1 + layer * HH * HH; const float* b1 = P.b1 + layer * HH;
    const float* W2  = P.W2 + layer * HH * HH; const float* b2 = P.b2 + layer * HH;
    const float* g2  = P.ln2_g + layer * HH; const float* be2 = P.ln2_b + layer * HH;
    __syncthreads();                       // LDS reuse guard
    {
        float4 a = ((const float4*)(P.seqs + r0g * HH))[t];
        float4 o = ((const float4*)(P.AO + r0g * HH))[t];
        a.x += o.x; a.y += o.y; a.z += o.z; a.w += o.w;
        ((float4*)s_lds)[t] = a;
    }
    __syncthreads();
    int w = t >> 6, lane = t & 63;
    int lrow = w * 2 + (lane >> 5), cl = lane & 31;
    // LN1 in-place
    {
        float sm = 0.f;
#pragma unroll
        for (int j = 0; j < 4; ++j) sm += s_lds[lrow][cl + 32 * j];
        sm += __shfl_xor(sm, 1, 64);  sm += __shfl_xor(sm, 2, 64);
        sm += __shfl_xor(sm, 4, 64);  sm += __shfl_xor(sm, 8, 64);
        sm += __shfl_xor(sm, 16, 64);
        float mean = sm * (1.0f / HH);
        float vr = 0.f;
#pragma unroll
        for (int j = 0; j < 4; ++j) {
            float d = s_lds[lrow][cl + 32 * j] - mean;
            vr += d * d;
        }
        vr += __shfl_xor(vr, 1, 64);  vr += __shfl_xor(vr, 2, 64);
        vr += __shfl_xor(vr, 4, 64);  vr += __shfl_xor(vr, 8, 64);
        vr += __shfl_xor(vr, 16, 64);
        float rstd = rsqrtf(vr * (1.0f / HH) + 1e-8f);
#pragma unroll
        for (int j = 0; j < 4; ++j) {
            int c = cl + 32 * j;
            s_lds[lrow][c] = (s_lds[lrow][c] - mean) * rstd * g1[c] + be1[c];
        }
    }
    __syncthreads();
    // GEMM1 + relu
    int c = t & 127, rg = t >> 7;
    float acc[4] = {0.f, 0.f, 0.f, 0.f};
    const float4* w14 = (const float4*)(W1 + c * HH);
#pragma unroll 4
    for (int k4 = 0; k4 < HH / 4; ++k4) {
        float4 ww = w14[k4];
#pragma unroll
        for (int r = 0; r < 4; ++r) {
            float4 s = *(const float4*)&s_lds[rg * 4 + r][k4 * 4];
            acc[r] += s.x * ww.x + s.y * ww.y + s.z * ww.z + s.w * ww.w;
        }
    }
#pragma unroll
    for (int r = 0; r < 4; ++r) h_lds[rg * 4 + r][c] = fmaxf(acc[r] + b1[c], 0.f);
    __syncthreads();
    // GEMM2
#pragma unroll
    for (int r = 0; r < 4; ++r) acc[r] = 0.f;
    const float4* w24 = (const float4*)(W2 + c * HH);
#pragma unroll 4
    for (int k4 = 0; k4 < HH / 4; ++k4) {
        float4 ww = w24[k4];
#pragma unroll
        for (int r = 0; r < 4; ++r) {
            float4 s = *(const float4*)&h_lds[rg * 4 + r][k4 * 4];
            acc[r] += s.x * ww.x + s.y * ww.y + s.z * ww.z + s.w * ww.w;
        }
    }
    __syncthreads();
#pragma unroll
    for (int r = 0; r < 4; ++r)
        h_lds[rg * 4 + r][c] = s_lds[rg * 4 + r][c] + acc[r] + b2[c];
    __syncthreads();
    // LN2 + keep; final layer: lnf LN + logits
    {
        float sm = 0.f;
#pragma unroll
        for (int j = 0; j < 4; ++j) sm += h_lds[lrow][cl + 32 * j];
        sm += __shfl_xor(sm, 1, 64);  sm += __shfl_xor(sm, 2, 64);
        sm += __shfl_xor(sm, 4, 64);  sm += __shfl_xor(sm, 8, 64);
        sm += __shfl_xor(sm, 16, 64);
        float mean = sm * (1.0f / HH);
        float vr = 0.f;
#pragma unroll
        for (int j = 0; j < 4; ++j) {
            float d = h_lds[lrow][cl + 32 * j] - mean;
            vr += d * d;
        }
        vr += __shfl_xor(vr, 1, 64);  vr += __shfl_xor(vr, 2, 64);
        vr += __shfl_xor(vr, 4, 64);  vr += __shfl_xor(vr, 8, 64);
        vr += __shfl_xor(vr, 16, 64);
        float rstd = rsqrtf(vr * (1.0f / HH) + 1e-8f);
        int row = r0g + lrow;
        float keep = (P.log_seqs[row] != 0) ? 1.0f : 0.0f;
        float y2[4];
#pragma unroll
        for (int j = 0; j < 4; ++j) {
            int cc = cl + 32 * j;
            y2[j] = ((h_lds[lrow][cc] - mean) * rstd * g2[cc] + be2[cc]) * keep;
        }
        if (!do_final) {
#pragma unroll
            for (int j = 0; j < 4; ++j)
                P.seqs[row * HH + cl + 32 * j] = y2[j];
        } else {
            float sm2 = y2[0] + y2[1] + y2[2] + y2[3];
            sm2 += __shfl_xor(sm2, 1, 64);  sm2 += __shfl_xor(sm2, 2, 64);
            sm2 += __shfl_xor(sm2, 4, 64);  sm2 += __shfl_xor(sm2, 8, 64);
            sm2 += __shfl_xor(sm2, 16, 64);
            float mean2 = sm2 * (1.0f / HH);
            float vr2 = 0.f;
#pragma unroll
            for (int j = 0; j < 4; ++j) {
                float d = y2[j] - mean2;
                vr2 += d * d;
            }
            vr2 += __shfl_xor(vr2, 1, 64);  vr2 += __shfl_xor(vr2, 2, 64);
            vr2 += __shfl_xor(vr2, 4, 64);  vr2 += __shfl_xor(vr2, 8, 64);
            vr2 += __shfl_xor(vr2, 16, 64);
            float rstd2 = rsqrtf(vr2 * (1.0f / HH) + 1e-8f);
            int pid = P.pos_seqs[row];
            int nid = P.neg_seqs[row];
            float pp = 0.f, nn = 0.f;
#pragma unroll
            for (int j = 0; j < 4; ++j) {
                int cc = cl + 32 * j;
                float lf = (y2[j] - mean2) * rstd2 * P.lnf_g[cc] + P.lnf_b[cc];
                pp += lf * P.item_emb[pid * HH + cc];
                nn += lf * P.item_emb[nid * HH + cc];
            }
            pp += __shfl_xor(pp, 1, 64);  pp += __shfl_xor(pp, 2, 64);
            pp += __shfl_xor(pp, 4, 64);  pp += __shfl_xor(pp, 8, 64);
            pp += __shfl_xor(pp, 16, 64);
            nn += __shfl_xor(nn, 1, 64);  nn += __shfl_xor(nn, 2, 64);
            nn += __shfl_xor(nn, 4, 64);  nn += __shfl_xor(nn, 8, 64);
            nn += __shfl_xor(nn, 16, 64);
            if (cl == 0) {
                P.out[row] = pp;
                P.out[BB * LL + row] = nn;
            }
        }
    }
}

// ---- mega-kernel: all phases, grid.sync() between ----
__global__ __launch_bounds__(256, 4) void k_mega(Params P) {
    cg::grid_group grid = cg::this_grid();
    __shared__ float smem[7660];   // max phase footprint: attn = 2176 + 5484
    __shared__ int s_allmask;
    for (int layer = 0; layer < 2; ++layer) {
        for (int tile = blockIdx.x; tile < 400; tile += gridDim.x)
            ph_qkv(P, smem, tile, layer);
        grid.sync();
        for (int tile = blockIdx.x; tile < 800; tile += gridDim.x)
            ph_proj(P, smem, tile);
        grid.sync();
        for (int tile = blockIdx.x; tile < 800; tile += gridDim.x)
            ph_attn(P, smem, &s_allmask, tile);
        grid.sync();
        for (int tile = blockIdx.x; tile < 400; tile += gridDim.x)
            ph_ffn(P, smem, tile, layer);
        if (layer == 0) grid.sync();
    }
}

extern "C" void kernel_launch(void* const* d_in, const int* in_sizes, int n_in,
                              void* d_out, int out_size, void* d_ws, size_t ws_size,
                              hipStream_t stream) {
    Params P;
    P.log_seqs = (const int*)d_in[1];
    P.tm       = (const int*)d_in[2];
    P.pos_seqs = (const int*)d_in[3];
    P.neg_seqs = (const int*)d_in[4];
    P.item_emb = (const float*)d_in[5];
    P.posK  = (const float*)d_in[6];
    P.posV  = (const float*)d_in[7];
    P.timeK = (const float*)d_in[8];
    P.timeV = (const float*)d_in[9];
    P.Wq = (const float*)d_in[10]; P.bq = (const float*)d_in[11];
    P.Wk = (const float*)d_in[12]; P.bk = (const float*)d_in[13];
    P.Wv = (const float*)d_in[14]; P.bv = (const float*)d_in[15];
    P.ln1_g = (const float*)d_in[16]; P.ln1_b = (const float*)d_in[17];
    P.W1 = (const float*)d_in[18]; P.b1 = (const float*)d_in[19];
    P.W2 = (const float*)d_in[20]; P.b2 = (const float*)d_in[21];
    P.ln2_g = (const float*)d_in[22]; P.ln2_b = (const float*)d_in[23];
    P.lnf_g = (const float*)d_in[24]; P.lnf_b = (const float*)d_in[25];

    float* ws = (float*)d_ws;
    P.seqs  = ws;
    P.Q     = ws + 409600;
    P.Kp    = ws + 2 * 409600;
    P.Vp    = ws + 3 * 409600;
    P.AO    = ws + 4 * 409600;
    P.projK = ws + 5 * 409600;           // 32*200*257 = 1,644,800
    P.out   = (float*)d_out;

    int maxBlk = 0;
    if (hipOccupancyMaxActiveBlocksPerMultiprocessor(&maxBlk, (const void*)k_mega,
                                                     256, 0) != hipSuccess || maxBlk < 1)
        maxBlk = 1;
    unsigned grid = (unsigned)maxBlk * 256u;   // 256 CUs on MI355X
    if (grid > 800u) grid = 800u;

    void* args[] = { (void*)&P };
    hipLaunchCooperativeKernel((const void*)k_mega, dim3(grid), dim3(256),
                               args, 0, stream);
}

// Round 13
// 266.875 us; speedup vs baseline: 2.4746x; 2.4746x over previous
//
#include <hip/hip_runtime.h>
#include <hip/hip_bf16.h>
#include <math.h>

#define BB 16
#define LL 200
#define HH 128
#define DD 64
#define NQT 25          // 200/8 q-tiles
#define NEGF -4294967295.0f
#define SQRTH 11.313708498984761f

// ---------------- QKV projection (16 rows/block, 512 threads), optional embed ----------------
__global__ __launch_bounds__(512) void k_qkv(float* __restrict__ seqs,
    const int* __restrict__ log_seqs, const float* __restrict__ item_emb, int do_embed,
    const float* __restrict__ Wq, const float* __restrict__ bq,
    const float* __restrict__ Wk, const float* __restrict__ bk,
    const float* __restrict__ Wv, const float* __restrict__ bv,
    const float* __restrict__ posK, const float* __restrict__ posV,
    float* __restrict__ Q, float* __restrict__ Kp, float* __restrict__ Vp) {
    __shared__ float s_lds[16][HH];
    int r0g = blockIdx.x * 16;
    int t = threadIdx.x;
    if (do_embed) {
        int r = t >> 5, d4 = t & 31;          // 16 rows x 32 float4
        int id = log_seqs[r0g + r];
        float4 v = make_float4(0.f, 0.f, 0.f, 0.f);
        if (id != 0) {
            v = ((const float4*)(item_emb + id * HH))[d4];
            v.x *= SQRTH; v.y *= SQRTH; v.z *= SQRTH; v.w *= SQRTH;
        }
        *(float4*)&s_lds[r][d4 * 4] = v;
        ((float4*)(seqs + r0g * HH))[t] = v;
    } else {
        ((float4*)s_lds)[t] = ((const float4*)(seqs + r0g * HH))[t];
    }
    __syncthreads();
    int c = t & 127, rg = t >> 7;
    float aq[4] = {0.f, 0.f, 0.f, 0.f};
    float ak[4] = {0.f, 0.f, 0.f, 0.f};
    float av[4] = {0.f, 0.f, 0.f, 0.f};
    const float4* wq4 = (const float4*)(Wq + c * HH);
    const float4* wk4 = (const float4*)(Wk + c * HH);
    const float4* wv4 = (const float4*)(Wv + c * HH);
#pragma unroll 4
    for (int k4 = 0; k4 < HH / 4; ++k4) {
        float4 wq = wq4[k4], wk = wk4[k4], wv = wv4[k4];
#pragma unroll
        for (int r = 0; r < 4; ++r) {
            float4 s = *(const float4*)&s_lds[rg * 4 + r][k4 * 4];
            aq[r] += s.x * wq.x + s.y * wq.y + s.z * wq.z + s.w * wq.w;
            ak[r] += s.x * wk.x + s.y * wk.y + s.z * wk.z + s.w * wk.w;
            av[r] += s.x * wv.x + s.y * wv.y + s.z * wv.z + s.w * wv.w;
        }
    }
#pragma unroll
    for (int r = 0; r < 4; ++r) {
        int row = r0g + rg * 4 + r;
        int l = row % LL;
        Q[row * HH + c]  = aq[r] + bq[c];
        Kp[row * HH + c] = ak[r] + bk[c] + posK[l * HH + c];
        Vp[row * HH + c] = av[r] + bv[c] + posV[l * HH + c];
    }
}

// ---------------- projK[bh,q,tt] = Q[b,q,h,:] . timeK[tt,h,:] ----------------
// grid = 32 bh * 25 qtiles(8); 256 threads: tq = t>>5, ttl = t&31
__global__ __launch_bounds__(256) void k_proj(const float* __restrict__ Q,
    const float* __restrict__ timeK, float* __restrict__ projK) {
    int bh = blockIdx.x / 25, qt = blockIdx.x % 25;
    int b = bh >> 1, h = bh & 1;
    int qlo = qt * 8;
    __shared__ float Qs[8][68];
    __shared__ float TK[32][68];
    int t = threadIdx.x;
    if (t < 128) {
        int r = t >> 4, d4 = t & 15;
        *(float4*)&Qs[r][d4 * 4] =
            ((const float4*)(Q + (b * LL + qlo + r) * HH + h * DD))[d4];
    }
    int tq = t >> 5, ttl = t & 31;
    for (int ch = 0; ch < 9; ++ch) {
        int base = ch * 32;
        __syncthreads();                 // protect TK (and Qs on ch==0)
        for (int x = t; x < 512; x += 256) {
            int i = x >> 4, d4 = x & 15;
            int tt = base + i;
            if (tt < 257)
                *(float4*)&TK[i][d4 * 4] =
                    ((const float4*)(timeK + tt * HH + h * DD))[d4];
        }
        __syncthreads();
        int tt = base + ttl;
        if (tt < 257) {
            float acc = 0.f;
#pragma unroll
            for (int d4 = 0; d4 < 16; ++d4) {
                float4 qv = *(const float4*)&Qs[tq][d4 * 4];
                float4 kv = *(const float4*)&TK[ttl][d4 * 4];
                acc += qv.x * kv.x + qv.y * kv.y + qv.z * kv.z + qv.w * kv.w;
            }
            projK[(bh * LL + qlo + tq) * 257 + tt] = acc;
        }
    }
}

// ---------------- fused scores + register-softmax + hist + PV ----------------
// grid = 32 bh * 25 qtiles(8); 256 threads: tq/g = t>>5, lane = t&31
__global__ __launch_bounds__(256) void k_attn(
    const float* __restrict__ Q, const float* __restrict__ Kp, const float* __restrict__ Vp,
    const float* __restrict__ projK, const float* __restrict__ timeV,
    const int* __restrict__ tm, const int* __restrict__ log_seqs,
    float* __restrict__ attnout) {
    int bh = blockIdx.x / NQT, qt = blockIdx.x % NQT;
    int b = bh >> 1, h = bh & 1;
    int qlo = qt * 8;
    __shared__ float K_s[32][68];
    __shared__ float smemW[457 * 12];        // WT(i,j)=smemW[i*12+j]; probs 0..199, hist 200..456
    __shared__ int s_allmask;
#define WT(i, j) smemW[(i) * 12 + (j)]
    int t = threadIdx.x;
    int tq = t >> 5, lane = t & 31, g = tq;
    int q = qlo + tq;
    int qhi = qlo + 7;

    if (t == 0) s_allmask = 0;
    for (int x = 200 * 12 + t; x < 457 * 12; x += 256) smemW[x] = 0.f;
    float4 qreg[16];
    {
        const float4* qp = (const float4*)(Q + (b * LL + q) * HH + h * DD);
#pragma unroll
        for (int d4 = 0; d4 < 16; ++d4) qreg[d4] = qp[d4];
    }
    const int* tmrow = tm + (b * LL + q) * LL;
    const float* projrow = projK + (bh * LL + q) * 257;
    const int* lsrow = log_seqs + b * LL;

    // phase 1: scores into registers s[7]
    float s[7];
#pragma unroll
    for (int j = 0; j < 7; ++j) s[j] = NEGF;
    int nkc = (qhi >> 5) + 1;                // block-uniform, 1..7
#pragma unroll
    for (int kc = 0; kc < 7; ++kc) {
        if (kc < nkc) {
            int kbase = kc * 32;
            for (int x = t; x < 512; x += 256) {
                int i = x >> 4, d4 = x & 15;
                int k = kbase + i;
                if (k < LL)
                    *(float4*)&K_s[i][d4 * 4] =
                        ((const float4*)(Kp + (b * LL + k) * HH + h * DD))[d4];
            }
            __syncthreads();
            int k = kbase + lane;
            if (k <= q && lsrow[k] != 0) {
                float acc = 0.f;
#pragma unroll
                for (int d4 = 0; d4 < 16; ++d4) {
                    float4 kv = *(const float4*)&K_s[lane][d4 * 4];
                    acc += qreg[d4].x * kv.x + qreg[d4].y * kv.y +
                           qreg[d4].z * kv.z + qreg[d4].w * kv.w;
                }
                s[kc] = (acc + projrow[tmrow[k]]) * 0.125f;
            }
            __syncthreads();
        }
    }

    // phase 2: softmax fully in registers (32 lanes per q row)
    float mx = s[0];
#pragma unroll
    for (int j = 1; j < 7; ++j) mx = fmaxf(mx, s[j]);
    mx = fmaxf(mx, __shfl_xor(mx, 1, 64));
    mx = fmaxf(mx, __shfl_xor(mx, 2, 64));
    mx = fmaxf(mx, __shfl_xor(mx, 4, 64));
    mx = fmaxf(mx, __shfl_xor(mx, 8, 64));
    mx = fmaxf(mx, __shfl_xor(mx, 16, 64));
    bool allmask = (mx == NEGF);             // exp(0)=1 per k -> uniform 1/200, matches ref
    float sum = 0.f;
#pragma unroll
    for (int j = 0; j < 7; ++j) {
        int k = lane + 32 * j;
        float e = (k < LL) ? __expf(s[j] - mx) : 0.f;
        s[j] = e;
        sum += e;
    }
    sum += __shfl_xor(sum, 1, 64);
    sum += __shfl_xor(sum, 2, 64);
    sum += __shfl_xor(sum, 4, 64);
    sum += __shfl_xor(sum, 8, 64);
    sum += __shfl_xor(sum, 16, 64);
    float inv = 1.0f / sum;
    int klim = allmask ? LL : (q + 1);
    if (allmask && lane == 0) s_allmask = 1;
#pragma unroll
    for (int j = 0; j < 7; ++j) {
        int k = lane + 32 * j;
        if (k < LL) {
            float p = s[j] * inv;
            WT(k, tq) = p;
            if (k < klim && p != 0.f)
                atomicAdd(&WT(200 + tmrow[k], tq), p);
        }
    }
    __syncthreads();

    // phase 3: PV — direct coalesced global reads, broadcast LDS weights
    int kmax = s_allmask ? LL : (qhi + 1);
    float a00=0.f,a01=0.f,a10=0.f,a11=0.f,a20=0.f,a21=0.f,a30=0.f,a31=0.f;
    float a40=0.f,a41=0.f,a50=0.f,a51=0.f,a60=0.f,a61=0.f,a70=0.f,a71=0.f;
#define PV_STEP(WROW, SRCPTR)                                            \
    {                                                                    \
        const float* wr = &WROW;                                         \
        float4 w0 = *(const float4*)wr;                                  \
        float4 w1 = *(const float4*)(wr + 4);                            \
        float2 vv = *(const float2*)(SRCPTR);                            \
        a00 += w0.x * vv.x; a01 += w0.x * vv.y;                          \
        a10 += w0.y * vv.x; a11 += w0.y * vv.y;                          \
        a20 += w0.z * vv.x; a21 += w0.z * vv.y;                          \
        a30 += w0.w * vv.x; a31 += w0.w * vv.y;                          \
        a40 += w1.x * vv.x; a41 += w1.x * vv.y;                          \
        a50 += w1.y * vv.x; a51 += w1.y * vv.y;                          \
        a60 += w1.z * vv.x; a61 += w1.z * vv.y;                          \
        a70 += w1.w * vv.x; a71 += w1.w * vv.y;                          \
    }
    for (int i = g; i < kmax; i += 8)
        PV_STEP(WT(i, 0), Vp + (b * LL + i) * HH + h * DD + lane * 2);
    for (int i = g; i < 257; i += 8)
        PV_STEP(WT(200 + i, 0), timeV + i * HH + h * DD + lane * 2);
#undef PV_STEP
    __syncthreads();
    float* part = smemW;
    part[g * 512 + 0 * 64 + lane * 2] = a00; part[g * 512 + 0 * 64 + lane * 2 + 1] = a01;
    part[g * 512 + 1 * 64 + lane * 2] = a10; part[g * 512 + 1 * 64 + lane * 2 + 1] = a11;
    part[g * 512 + 2 * 64 + lane * 2] = a20; part[g * 512 + 2 * 64 + lane * 2 + 1] = a21;
    part[g * 512 + 3 * 64 + lane * 2] = a30; part[g * 512 + 3 * 64 + lane * 2 + 1] = a31;
    part[g * 512 + 4 * 64 + lane * 2] = a40; part[g * 512 + 4 * 64 + lane * 2 + 1] = a41;
    part[g * 512 + 5 * 64 + lane * 2] = a50; part[g * 512 + 5 * 64 + lane * 2 + 1] = a51;
    part[g * 512 + 6 * 64 + lane * 2] = a60; part[g * 512 + 6 * 64 + lane * 2 + 1] = a61;
    part[g * 512 + 7 * 64 + lane * 2] = a70; part[g * 512 + 7 * 64 + lane * 2 + 1] = a71;
    __syncthreads();
    {
        float ox = 0.f, oy = 0.f;
#pragma unroll
        for (int gg = 0; gg < 8; ++gg) {
            ox += part[gg * 512 + tq * 64 + lane * 2];
            oy += part[gg * 512 + tq * 64 + lane * 2 + 1];
        }
        *(float2*)(attnout + (b * LL + q) * HH + h * DD + lane * 2) =
            make_float2(ox, oy);
    }
#undef WT
}

// ---------------- FFN, high-TLP: 4 rows/block, 512 threads, grid 800 ----------------
// s1=LN1(seqs+AO); x2=s1+FFN(s1); y2=LN2(x2)*keep -> seqs   (or lnf+logits if do_final)
// LN reductions: waves 2r,2r+1 both own row r redundantly (64-lane shuffle reduce).
__global__ __launch_bounds__(512) void k_ffn(
    float* __restrict__ seqs, const float* __restrict__ AO,
    const float* __restrict__ g1, const float* __restrict__ be1,
    const float* __restrict__ W1, const float* __restrict__ b1,
    const float* __restrict__ W2, const float* __restrict__ b2,
    const float* __restrict__ g2, const float* __restrict__ be2,
    const int* __restrict__ log_seqs, int do_final,
    const float* __restrict__ lnf_g, const float* __restrict__ lnf_b,
    const float* __restrict__ item_emb,
    const int* __restrict__ pos_seqs, const int* __restrict__ neg_seqs,
    float* __restrict__ out) {
    __shared__ float s_lds[4][HH];     // s1
    __shared__ float h_lds[4][HH];     // h1, then x2
    int r0g = blockIdx.x * 4;
    int t = threadIdx.x;
    int wv = t >> 6, lane = t & 63;
    int lrow = wv >> 1, par = wv & 1;  // 2 waves per row

    if (t < 128) {
        float4 a = ((const float4*)(seqs + r0g * HH))[t];
        float4 o = ((const float4*)(AO + r0g * HH))[t];
        a.x += o.x; a.y += o.y; a.z += o.z; a.w += o.w;
        ((float4*)s_lds)[t] = a;
    }
    __syncthreads();
    // LN1 (redundant per wave pair): lane covers cols lane, lane+64
    {
        float x0 = s_lds[lrow][lane], x1 = s_lds[lrow][lane + 64];
        float sm = x0 + x1;
        sm += __shfl_xor(sm, 1, 64);  sm += __shfl_xor(sm, 2, 64);
        sm += __shfl_xor(sm, 4, 64);  sm += __shfl_xor(sm, 8, 64);
        sm += __shfl_xor(sm, 16, 64); sm += __shfl_xor(sm, 32, 64);
        float mean = sm * (1.0f / HH);
        float d0 = x0 - mean, d1 = x1 - mean;
        float vr = d0 * d0 + d1 * d1;
        vr += __shfl_xor(vr, 1, 64);  vr += __shfl_xor(vr, 2, 64);
        vr += __shfl_xor(vr, 4, 64);  vr += __shfl_xor(vr, 8, 64);
        vr += __shfl_xor(vr, 16, 64); vr += __shfl_xor(vr, 32, 64);
        float rstd = rsqrtf(vr * (1.0f / HH) + 1e-8f);
        int cw = lane + par * 64;
        float dn = par ? d1 : d0;
        __syncthreads();               // all reads done before overwrite
        s_lds[lrow][cw] = dn * rstd * g1[cw] + be1[cw];
    }
    __syncthreads();
    // GEMM1 + relu: row = t>>7, col = t&127, one 128-dot per thread
    int row = t >> 7, col = t & 127;
    {
        float acc = 0.f;
        const float4* w4 = (const float4*)(W1 + col * HH);
        const float4* s4 = (const float4*)&s_lds[row][0];
#pragma unroll 8
        for (int k4 = 0; k4 < 32; ++k4) {
            float4 w = w4[k4];
            float4 s = s4[k4];
            acc += s.x * w.x + s.y * w.y + s.z * w.z + s.w * w.w;
        }
        h_lds[row][col] = fmaxf(acc + b1[col], 0.f);
    }
    __syncthreads();
    // GEMM2 + residual: x2
    float x2;
    {
        float acc = 0.f;
        const float4* w4 = (const float4*)(W2 + col * HH);
        const float4* h4 = (const float4*)&h_lds[row][0];
#pragma unroll 8
        for (int k4 = 0; k4 < 32; ++k4) {
            float4 w = w4[k4];
            float4 s = h4[k4];
            acc += s.x * w.x + s.y * w.y + s.z * w.z + s.w * w.w;
        }
        x2 = s_lds[row][col] + acc + b2[col];
    }
    __syncthreads();                   // h_lds reads done
    h_lds[row][col] = x2;
    __syncthreads();
    // LN2 + keep (redundant per wave pair)
    {
        float x0 = h_lds[lrow][lane], x1 = h_lds[lrow][lane + 64];
        float sm = x0 + x1;
        sm += __shfl_xor(sm, 1, 64);  sm += __shfl_xor(sm, 2, 64);
        sm += __shfl_xor(sm, 4, 64);  sm += __shfl_xor(sm, 8, 64);
        sm += __shfl_xor(sm, 16, 64); sm += __shfl_xor(sm, 32, 64);
        float mean = sm * (1.0f / HH);
        float d0 = x0 - mean, d1 = x1 - mean;
        float vr = d0 * d0 + d1 * d1;
        vr += __shfl_xor(vr, 1, 64);  vr += __shfl_xor(vr, 2, 64);
        vr += __shfl_xor(vr, 4, 64);  vr += __shfl_xor(vr, 8, 64);
        vr += __shfl_xor(vr, 16, 64); vr += __shfl_xor(vr, 32, 64);
        float rstd = rsqrtf(vr * (1.0f / HH) + 1e-8f);
        int grow = r0g + lrow;
        float keep = (log_seqs[grow] != 0) ? 1.0f : 0.0f;
        float y0 = (d0 * rstd * g2[lane] + be2[lane]) * keep;
        float y1 = (d1 * rstd * g2[lane + 64] + be2[lane + 64]) * keep;
        if (!do_final) {
            if (par == 0) seqs[grow * HH + lane] = y0;
            else          seqs[grow * HH + lane + 64] = y1;
        } else {
            // lnf LayerNorm on y, then pos/neg logits
            float sm2 = y0 + y1;
            sm2 += __shfl_xor(sm2, 1, 64);  sm2 += __shfl_xor(sm2, 2, 64);
            sm2 += __shfl_xor(sm2, 4, 64);  sm2 += __shfl_xor(sm2, 8, 64);
            sm2 += __shfl_xor(sm2, 16, 64); sm2 += __shfl_xor(sm2, 32, 64);
            float mean2 = sm2 * (1.0f / HH);
            float e0 = y0 - mean2, e1 = y1 - mean2;
            float vr2 = e0 * e0 + e1 * e1;
            vr2 += __shfl_xor(vr2, 1, 64);  vr2 += __shfl_xor(vr2, 2, 64);
            vr2 += __shfl_xor(vr2, 4, 64);  vr2 += __shfl_xor(vr2, 8, 64);
            vr2 += __shfl_xor(vr2, 16, 64); vr2 += __shfl_xor(vr2, 32, 64);
            float rstd2 = rsqrtf(vr2 * (1.0f / HH) + 1e-8f);
            int pid = pos_seqs[grow];
            int nid = neg_seqs[grow];
            float lf0 = e0 * rstd2 * lnf_g[lane] + lnf_b[lane];
            float lf1 = e1 * rstd2 * lnf_g[lane + 64] + lnf_b[lane + 64];
            float pp = lf0 * item_emb[pid * HH + lane] + lf1 * item_emb[pid * HH + lane + 64];
            float nn = lf0 * item_emb[nid * HH + lane] + lf1 * item_emb[nid * HH + lane + 64];
            pp += __shfl_xor(pp, 1, 64);  pp += __shfl_xor(pp, 2, 64);
            pp += __shfl_xor(pp, 4, 64);  pp += __shfl_xor(pp, 8, 64);
            pp += __shfl_xor(pp, 16, 64); pp += __shfl_xor(pp, 32, 64);
            nn += __shfl_xor(nn, 1, 64);  nn += __shfl_xor(nn, 2, 64);
            nn += __shfl_xor(nn, 4, 64);  nn += __shfl_xor(nn, 8, 64);
            nn += __shfl_xor(nn, 16, 64); nn += __shfl_xor(nn, 32, 64);
            if (par == 0 && lane == 0) {
                out[grow] = pp;
                out[BB * LL + grow] = nn;
            }
        }
    }
}

extern "C" void kernel_launch(void* const* d_in, const int* in_sizes, int n_in,
                              void* d_out, int out_size, void* d_ws, size_t ws_size,
                              hipStream_t stream) {
    const int* log_seqs = (const int*)d_in[1];
    const int* tm       = (const int*)d_in[2];
    const int* pos_seqs = (const int*)d_in[3];
    const int* neg_seqs = (const int*)d_in[4];
    const float* item_emb = (const float*)d_in[5];
    const float* posK   = (const float*)d_in[6];
    const float* posV   = (const float*)d_in[7];
    const float* timeK  = (const float*)d_in[8];
    const float* timeV  = (const float*)d_in[9];
    const float* Wq = (const float*)d_in[10];
    const float* bq = (const float*)d_in[11];
    const float* Wk = (const float*)d_in[12];
    const float* bk = (const float*)d_in[13];
    const float* Wv = (const float*)d_in[14];
    const float* bv = (const float*)d_in[15];
    const float* ln1_g = (const float*)d_in[16];
    const float* ln1_b = (const float*)d_in[17];
    const float* W1 = (const float*)d_in[18];
    const float* b1 = (const float*)d_in[19];
    const float* W2 = (const float*)d_in[20];
    const float* b2 = (const float*)d_in[21];
    const float* ln2_g = (const float*)d_in[22];
    const float* ln2_b = (const float*)d_in[23];
    const float* lnf_g = (const float*)d_in[24];
    const float* lnf_b = (const float*)d_in[25];

    float* ws    = (float*)d_ws;
    float* seqs  = ws;                   // 409600 floats each
    float* Qb    = seqs + 409600;
    float* Kpb   = Qb + 409600;
    float* Vpb   = Kpb + 409600;
    float* AO    = Vpb + 409600;
    float* projK = AO + 409600;          // 32*200*257 = 1,644,800

    for (int i = 0; i < 2; ++i) {
        k_qkv<<<BB * LL / 16, 512, 0, stream>>>(seqs, log_seqs, item_emb,
            (i == 0) ? 1 : 0,
            Wq + i * HH * HH, bq + i * HH,
            Wk + i * HH * HH, bk + i * HH,
            Wv + i * HH * HH, bv + i * HH,
            posK, posV, Qb, Kpb, Vpb);
        k_proj<<<32 * NQT, 256, 0, stream>>>(Qb, timeK, projK);
        k_attn<<<32 * NQT, 256, 0, stream>>>(Qb, Kpb, Vpb, projK, timeV,
                                             tm, log_seqs, AO);
        k_ffn<<<BB * LL / 4, 512, 0, stream>>>(seqs, AO,
            ln1_g + i * HH, ln1_b + i * HH,
            W1 + i * HH * HH, b1 + i * HH,
            W2 + i * HH * HH, b2 + i * HH,
            ln2_g + i * HH, ln2_b + i * HH, log_seqs,
            (i == 1) ? 1 : 0, lnf_g, lnf_b, item_emb,
            pos_seqs, neg_seqs, (float*)d_out);
    }
}

// Round 14
// 194.824 us; speedup vs baseline: 3.3898x; 1.3698x over previous
//
#include <hip/hip_runtime.h>
#include <hip/hip_bf16.h>
#include <math.h>

#define BB 16
#define LL 200
#define HH 128
#define DD 64
#define NQT 25          // 200/8 q-tiles
#define NEGF -4294967295.0f
#define SQRTH 11.313708498984761f

// ---------------- transpose the 10 weight matrices into WT[k][col] ----------------
// grid = 10 matrices * 16 tiles(32x32); order: Wq0,Wq1,Wk0,Wk1,Wv0,Wv1,W10,W11,W20,W21
__global__ __launch_bounds__(256) void k_prep(const float* __restrict__ Wq,
    const float* __restrict__ Wk, const float* __restrict__ Wv,
    const float* __restrict__ W1, const float* __restrict__ W2,
    float* __restrict__ WT) {
    int m = blockIdx.x >> 4, tile = blockIdx.x & 15;
    const float* base = (m < 2) ? Wq : (m < 4) ? Wk : (m < 6) ? Wv : (m < 8) ? W1 : W2;
    const float* src = base + (m & 1) * HH * HH;
    float* dst = WT + m * HH * HH;
    __shared__ float tb[32][33];
    int t = threadIdx.x;
    int tr = tile >> 2, tc = tile & 3;
    int lr = t >> 3, lc = (t & 7) * 4;
    float4 v = *(const float4*)(src + (tr * 32 + lr) * HH + tc * 32 + lc);
    tb[lr][lc + 0] = v.x; tb[lr][lc + 1] = v.y;
    tb[lr][lc + 2] = v.z; tb[lr][lc + 3] = v.w;
    __syncthreads();
    float4 o;
    o.x = tb[lc + 0][lr]; o.y = tb[lc + 1][lr];
    o.z = tb[lc + 2][lr]; o.w = tb[lc + 3][lr];
    *(float4*)(dst + (tc * 32 + lr) * HH + tr * 32 + lc) = o;
}

// ---------------- QKV projection, coalesced WT reads: 8 rows/block, 256 threads, grid 400 ----------------
__global__ __launch_bounds__(256) void k_qkv(float* __restrict__ seqs,
    const int* __restrict__ log_seqs, const float* __restrict__ item_emb, int do_embed,
    const float* __restrict__ WTq, const float* __restrict__ bq,
    const float* __restrict__ WTk, const float* __restrict__ bk,
    const float* __restrict__ WTv, const float* __restrict__ bv,
    const float* __restrict__ posK, const float* __restrict__ posV,
    float* __restrict__ Q, float* __restrict__ Kp, float* __restrict__ Vp) {
    __shared__ float s_lds[8][HH];
    int r0g = blockIdx.x * 8;
    int t = threadIdx.x;
    {
        int r = t >> 5, d4 = t & 31;          // 8 rows x 32 float4
        if (do_embed) {
            int id = log_seqs[r0g + r];
            float4 v = make_float4(0.f, 0.f, 0.f, 0.f);
            if (id != 0) {
                v = ((const float4*)(item_emb + id * HH))[d4];
                v.x *= SQRTH; v.y *= SQRTH; v.z *= SQRTH; v.w *= SQRTH;
            }
            *(float4*)&s_lds[r][d4 * 4] = v;
            ((float4*)(seqs + r0g * HH))[t] = v;
        } else {
            ((float4*)s_lds)[t] = ((const float4*)(seqs + r0g * HH))[t];
        }
    }
    __syncthreads();
    int r = t >> 5, j = t & 31;               // row, 4-col group
    const float4* wq4 = (const float4*)WTq + j;
    const float4* wk4 = (const float4*)WTk + j;
    const float4* wv4 = (const float4*)WTv + j;
    float4 aq = make_float4(0.f, 0.f, 0.f, 0.f);
    float4 ak = make_float4(0.f, 0.f, 0.f, 0.f);
    float4 av = make_float4(0.f, 0.f, 0.f, 0.f);
#pragma unroll 4
    for (int k = 0; k < HH; ++k) {
        float sv = s_lds[r][k];
        float4 wq = wq4[k * 32];
        float4 wk = wk4[k * 32];
        float4 wv = wv4[k * 32];
        aq.x += sv * wq.x; aq.y += sv * wq.y; aq.z += sv * wq.z; aq.w += sv * wq.w;
        ak.x += sv * wk.x; ak.y += sv * wk.y; ak.z += sv * wk.z; ak.w += sv * wk.w;
        av.x += sv * wv.x; av.y += sv * wv.y; av.z += sv * wv.z; av.w += sv * wv.w;
    }
    int row = r0g + r;
    int l = row % LL;
    {
        float4 b = ((const float4*)bq)[j];
        aq.x += b.x; aq.y += b.y; aq.z += b.z; aq.w += b.w;
        ((float4*)(Q + row * HH))[j] = aq;
    }
    {
        float4 b = ((const float4*)bk)[j];
        float4 p = ((const float4*)(posK + l * HH))[j];
        ak.x += b.x + p.x; ak.y += b.y + p.y; ak.z += b.z + p.z; ak.w += b.w + p.w;
        ((float4*)(Kp + row * HH))[j] = ak;
    }
    {
        float4 b = ((const float4*)bv)[j];
        float4 p = ((const float4*)(posV + l * HH))[j];
        av.x += b.x + p.x; av.y += b.y + p.y; av.z += b.z + p.z; av.w += b.w + p.w;
        ((float4*)(Vp + row * HH))[j] = av;
    }
}

// ---------------- projK[bh,q,tt] = Q[b,q,h,:] . timeK[tt,h,:] ----------------
// grid = 32 bh * 25 qtiles(8); 256 threads: tq = t>>5, ttl = t&31
__global__ __launch_bounds__(256) void k_proj(const float* __restrict__ Q,
    const float* __restrict__ timeK, float* __restrict__ projK) {
    int bh = blockIdx.x / 25, qt = blockIdx.x % 25;
    int b = bh >> 1, h = bh & 1;
    int qlo = qt * 8;
    __shared__ float Qs[8][68];
    __shared__ float TK[32][68];
    int t = threadIdx.x;
    if (t < 128) {
        int r = t >> 4, d4 = t & 15;
        *(float4*)&Qs[r][d4 * 4] =
            ((const float4*)(Q + (b * LL + qlo + r) * HH + h * DD))[d4];
    }
    int tq = t >> 5, ttl = t & 31;
    for (int ch = 0; ch < 9; ++ch) {
        int base = ch * 32;
        __syncthreads();                 // protect TK (and Qs on ch==0)
        for (int x = t; x < 512; x += 256) {
            int i = x >> 4, d4 = x & 15;
            int tt = base + i;
            if (tt < 257)
                *(float4*)&TK[i][d4 * 4] =
                    ((const float4*)(timeK + tt * HH + h * DD))[d4];
        }
        __syncthreads();
        int tt = base + ttl;
        if (tt < 257) {
            float acc = 0.f;
#pragma unroll
            for (int d4 = 0; d4 < 16; ++d4) {
                float4 qv = *(const float4*)&Qs[tq][d4 * 4];
                float4 kv = *(const float4*)&TK[ttl][d4 * 4];
                acc += qv.x * kv.x + qv.y * kv.y + qv.z * kv.z + qv.w * kv.w;
            }
            projK[(bh * LL + qlo + tq) * 257 + tt] = acc;
        }
    }
}

// ---------------- fused scores + register-softmax + hist + PV ----------------
// grid = 32 bh * 25 qtiles(8); 256 threads: tq/g = t>>5, lane = t&31
__global__ __launch_bounds__(256) void k_attn(
    const float* __restrict__ Q, const float* __restrict__ Kp, const float* __restrict__ Vp,
    const float* __restrict__ projK, const float* __restrict__ timeV,
    const int* __restrict__ tm, const int* __restrict__ log_seqs,
    float* __restrict__ attnout) {
    int bh = blockIdx.x / NQT, qt = blockIdx.x % NQT;
    int b = bh >> 1, h = bh & 1;
    int qlo = qt * 8;
    __shared__ float K_s[32][68];
    __shared__ float smemW[457 * 12];        // WT(i,j)=smemW[i*12+j]; probs 0..199, hist 200..456
    __shared__ int s_allmask;
#define WT(i, j) smemW[(i) * 12 + (j)]
    int t = threadIdx.x;
    int tq = t >> 5, lane = t & 31, g = tq;
    int q = qlo + tq;
    int qhi = qlo + 7;

    if (t == 0) s_allmask = 0;
    for (int x = 200 * 12 + t; x < 457 * 12; x += 256) smemW[x] = 0.f;
    float4 qreg[16];
    {
        const float4* qp = (const float4*)(Q + (b * LL + q) * HH + h * DD);
#pragma unroll
        for (int d4 = 0; d4 < 16; ++d4) qreg[d4] = qp[d4];
    }
    const int* tmrow = tm + (b * LL + q) * LL;
    const float* projrow = projK + (bh * LL + q) * 257;
    const int* lsrow = log_seqs + b * LL;

    // phase 1: scores into registers s[7]
    float s[7];
#pragma unroll
    for (int j = 0; j < 7; ++j) s[j] = NEGF;
    int nkc = (qhi >> 5) + 1;                // block-uniform, 1..7
#pragma unroll
    for (int kc = 0; kc < 7; ++kc) {
        if (kc < nkc) {
            int kbase = kc * 32;
            for (int x = t; x < 512; x += 256) {
                int i = x >> 4, d4 = x & 15;
                int k = kbase + i;
                if (k < LL)
                    *(float4*)&K_s[i][d4 * 4] =
                        ((const float4*)(Kp + (b * LL + k) * HH + h * DD))[d4];
            }
            __syncthreads();
            int k = kbase + lane;
            if (k <= q && lsrow[k] != 0) {
                float acc = 0.f;
#pragma unroll
                for (int d4 = 0; d4 < 16; ++d4) {
                    float4 kv = *(const float4*)&K_s[lane][d4 * 4];
                    acc += qreg[d4].x * kv.x + qreg[d4].y * kv.y +
                           qreg[d4].z * kv.z + qreg[d4].w * kv.w;
                }
                s[kc] = (acc + projrow[tmrow[k]]) * 0.125f;
            }
            __syncthreads();
        }
    }

    // phase 2: softmax fully in registers (32 lanes per q row)
    float mx = s[0];
#pragma unroll
    for (int j = 1; j < 7; ++j) mx = fmaxf(mx, s[j]);
    mx = fmaxf(mx, __shfl_xor(mx, 1, 64));
    mx = fmaxf(mx, __shfl_xor(mx, 2, 64));
    mx = fmaxf(mx, __shfl_xor(mx, 4, 64));
    mx = fmaxf(mx, __shfl_xor(mx, 8, 64));
    mx = fmaxf(mx, __shfl_xor(mx, 16, 64));
    bool allmask = (mx == NEGF);             // exp(0)=1 per k -> uniform 1/200, matches ref
    float sum = 0.f;
#pragma unroll
    for (int j = 0; j < 7; ++j) {
        int k = lane + 32 * j;
        float e = (k < LL) ? __expf(s[j] - mx) : 0.f;
        s[j] = e;
        sum += e;
    }
    sum += __shfl_xor(sum, 1, 64);
    sum += __shfl_xor(sum, 2, 64);
    sum += __shfl_xor(sum, 4, 64);
    sum += __shfl_xor(sum, 8, 64);
    sum += __shfl_xor(sum, 16, 64);
    float inv = 1.0f / sum;
    int klim = allmask ? LL : (q + 1);
    if (allmask && lane == 0) s_allmask = 1;
#pragma unroll
    for (int j = 0; j < 7; ++j) {
        int k = lane + 32 * j;
        if (k < LL) {
            float p = s[j] * inv;
            WT(k, tq) = p;
            if (k < klim && p != 0.f)
                atomicAdd(&WT(200 + tmrow[k], tq), p);
        }
    }
    __syncthreads();

    // phase 3: PV — direct coalesced global reads, broadcast LDS weights
    int kmax = s_allmask ? LL : (qhi + 1);
    float a00=0.f,a01=0.f,a10=0.f,a11=0.f,a20=0.f,a21=0.f,a30=0.f,a31=0.f;
    float a40=0.f,a41=0.f,a50=0.f,a51=0.f,a60=0.f,a61=0.f,a70=0.f,a71=0.f;
#define PV_STEP(WROW, SRCPTR)                                            \
    {                                                                    \
        const float* wr = &WROW;                                         \
        float4 w0 = *(const float4*)wr;                                  \
        float4 w1 = *(const float4*)(wr + 4);                            \
        float2 vv = *(const float2*)(SRCPTR);                            \
        a00 += w0.x * vv.x; a01 += w0.x * vv.y;                          \
        a10 += w0.y * vv.x; a11 += w0.y * vv.y;                          \
        a20 += w0.z * vv.x; a21 += w0.z * vv.y;                          \
        a30 += w0.w * vv.x; a31 += w0.w * vv.y;                          \
        a40 += w1.x * vv.x; a41 += w1.x * vv.y;                          \
        a50 += w1.y * vv.x; a51 += w1.y * vv.y;                          \
        a60 += w1.z * vv.x; a61 += w1.z * vv.y;                          \
        a70 += w1.w * vv.x; a71 += w1.w * vv.y;                          \
    }
    for (int i = g; i < kmax; i += 8)
        PV_STEP(WT(i, 0), Vp + (b * LL + i) * HH + h * DD + lane * 2);
    for (int i = g; i < 257; i += 8)
        PV_STEP(WT(200 + i, 0), timeV + i * HH + h * DD + lane * 2);
#undef PV_STEP
    __syncthreads();
    float* part = smemW;
    part[g * 512 + 0 * 64 + lane * 2] = a00; part[g * 512 + 0 * 64 + lane * 2 + 1] = a01;
    part[g * 512 + 1 * 64 + lane * 2] = a10; part[g * 512 + 1 * 64 + lane * 2 + 1] = a11;
    part[g * 512 + 2 * 64 + lane * 2] = a20; part[g * 512 + 2 * 64 + lane * 2 + 1] = a21;
    part[g * 512 + 3 * 64 + lane * 2] = a30; part[g * 512 + 3 * 64 + lane * 2 + 1] = a31;
    part[g * 512 + 4 * 64 + lane * 2] = a40; part[g * 512 + 4 * 64 + lane * 2 + 1] = a41;
    part[g * 512 + 5 * 64 + lane * 2] = a50; part[g * 512 + 5 * 64 + lane * 2 + 1] = a51;
    part[g * 512 + 6 * 64 + lane * 2] = a60; part[g * 512 + 6 * 64 + lane * 2 + 1] = a61;
    part[g * 512 + 7 * 64 + lane * 2] = a70; part[g * 512 + 7 * 64 + lane * 2 + 1] = a71;
    __syncthreads();
    {
        float ox = 0.f, oy = 0.f;
#pragma unroll
        for (int gg = 0; gg < 8; ++gg) {
            ox += part[gg * 512 + tq * 64 + lane * 2];
            oy += part[gg * 512 + tq * 64 + lane * 2 + 1];
        }
        *(float2*)(attnout + (b * LL + q) * HH + h * DD + lane * 2) =
            make_float2(ox, oy);
    }
#undef WT
}

// ---------------- FFN, coalesced WT reads: 8 rows/block, 256 threads, grid 400 ----------------
// s1=LN1(seqs+AO); x2=s1+FFN(s1); y2=LN2(x2)*keep -> seqs  (or lnf+logits if do_final)
__global__ __launch_bounds__(256) void k_ffn(
    float* __restrict__ seqs, const float* __restrict__ AO,
    const float* __restrict__ g1, const float* __restrict__ be1,
    const float* __restrict__ WT1, const float* __restrict__ b1,
    const float* __restrict__ WT2, const float* __restrict__ b2,
    const float* __restrict__ g2, const float* __restrict__ be2,
    const int* __restrict__ log_seqs, int do_final,
    const float* __restrict__ lnf_g, const float* __restrict__ lnf_b,
    const float* __restrict__ item_emb,
    const int* __restrict__ pos_seqs, const int* __restrict__ neg_seqs,
    float* __restrict__ out) {
    __shared__ float s_lds[8][HH];     // s1
    __shared__ float h_lds[8][HH];     // h1, then x2
    int r0g = blockIdx.x * 8;
    int t = threadIdx.x;
    {
        float4 a = ((const float4*)(seqs + r0g * HH))[t];
        float4 o = ((const float4*)(AO + r0g * HH))[t];
        a.x += o.x; a.y += o.y; a.z += o.z; a.w += o.w;
        ((float4*)s_lds)[t] = a;
    }
    __syncthreads();
    int w = t >> 6, lane = t & 63;
    int lrow = w * 2 + (lane >> 5), cl = lane & 31;   // 32 lanes per row
    // LN1 in-place
    {
        float sm = 0.f;
#pragma unroll
        for (int j = 0; j < 4; ++j) sm += s_lds[lrow][cl + 32 * j];
        sm += __shfl_xor(sm, 1, 64);  sm += __shfl_xor(sm, 2, 64);
        sm += __shfl_xor(sm, 4, 64);  sm += __shfl_xor(sm, 8, 64);
        sm += __shfl_xor(sm, 16, 64);
        float mean = sm * (1.0f / HH);
        float vr = 0.f;
#pragma unroll
        for (int j = 0; j < 4; ++j) {
            float d = s_lds[lrow][cl + 32 * j] - mean;
            vr += d * d;
        }
        vr += __shfl_xor(vr, 1, 64);  vr += __shfl_xor(vr, 2, 64);
        vr += __shfl_xor(vr, 4, 64);  vr += __shfl_xor(vr, 8, 64);
        vr += __shfl_xor(vr, 16, 64);
        float rstd = rsqrtf(vr * (1.0f / HH) + 1e-8f);
#pragma unroll
        for (int j = 0; j < 4; ++j) {
            int c = cl + 32 * j;
            s_lds[lrow][c] = (s_lds[lrow][c] - mean) * rstd * g1[c] + be1[c];
        }
    }
    __syncthreads();
    // GEMM1 + relu: thread (r, j) -> 4 cols, coalesced WT1 reads
    int r = t >> 5, j = t & 31;
    {
        const float4* w4 = (const float4*)WT1 + j;
        float4 acc = make_float4(0.f, 0.f, 0.f, 0.f);
#pragma unroll 4
        for (int k = 0; k < HH; ++k) {
            float sv = s_lds[r][k];
            float4 ww = w4[k * 32];
            acc.x += sv * ww.x; acc.y += sv * ww.y;
            acc.z += sv * ww.z; acc.w += sv * ww.w;
        }
        float4 b = ((const float4*)b1)[j];
        acc.x = fmaxf(acc.x + b.x, 0.f); acc.y = fmaxf(acc.y + b.y, 0.f);
        acc.z = fmaxf(acc.z + b.z, 0.f); acc.w = fmaxf(acc.w + b.w, 0.f);
        *(float4*)&h_lds[r][j * 4] = acc;
    }
    __syncthreads();
    // GEMM2 + residual -> x2
    float4 x2;
    {
        const float4* w4 = (const float4*)WT2 + j;
        float4 acc = make_float4(0.f, 0.f, 0.f, 0.f);
#pragma unroll 4
        for (int k = 0; k < HH; ++k) {
            float hv = h_lds[r][k];
            float4 ww = w4[k * 32];
            acc.x += hv * ww.x; acc.y += hv * ww.y;
            acc.z += hv * ww.z; acc.w += hv * ww.w;
        }
        float4 b = ((const float4*)b2)[j];
        float4 s1 = *(const float4*)&s_lds[r][j * 4];
        x2.x = s1.x + acc.x + b.x; x2.y = s1.y + acc.y + b.y;
        x2.z = s1.z + acc.z + b.z; x2.w = s1.w + acc.w + b.w;
    }
    __syncthreads();                   // h_lds reads done
    *(float4*)&h_lds[r][j * 4] = x2;
    __syncthreads();
    // LN2 + keep; final layer: lnf LN + logits
    {
        float sm = 0.f;
#pragma unroll
        for (int jj = 0; jj < 4; ++jj) sm += h_lds[lrow][cl + 32 * jj];
        sm += __shfl_xor(sm, 1, 64);  sm += __shfl_xor(sm, 2, 64);
        sm += __shfl_xor(sm, 4, 64);  sm += __shfl_xor(sm, 8, 64);
        sm += __shfl_xor(sm, 16, 64);
        float mean = sm * (1.0f / HH);
        float vr = 0.f;
#pragma unroll
        for (int jj = 0; jj < 4; ++jj) {
            float d = h_lds[lrow][cl + 32 * jj] - mean;
            vr += d * d;
        }
        vr += __shfl_xor(vr, 1, 64);  vr += __shfl_xor(vr, 2, 64);
        vr += __shfl_xor(vr, 4, 64);  vr += __shfl_xor(vr, 8, 64);
        vr += __shfl_xor(vr, 16, 64);
        float rstd = rsqrtf(vr * (1.0f / HH) + 1e-8f);
        int row = r0g + lrow;
        float keep = (log_seqs[row] != 0) ? 1.0f : 0.0f;
        float y2[4];
#pragma unroll
        for (int jj = 0; jj < 4; ++jj) {
            int cc = cl + 32 * jj;
            y2[jj] = ((h_lds[lrow][cc] - mean) * rstd * g2[cc] + be2[cc]) * keep;
        }
        if (!do_final) {
#pragma unroll
            for (int jj = 0; jj < 4; ++jj)
                seqs[row * HH + cl + 32 * jj] = y2[jj];
        } else {
            float sm2 = y2[0] + y2[1] + y2[2] + y2[3];
            sm2 += __shfl_xor(sm2, 1, 64);  sm2 += __shfl_xor(sm2, 2, 64);
            sm2 += __shfl_xor(sm2, 4, 64);  sm2 += __shfl_xor(sm2, 8, 64);
            sm2 += __shfl_xor(sm2, 16, 64);
            float mean2 = sm2 * (1.0f / HH);
            float vr2 = 0.f;
#pragma unroll
            for (int jj = 0; jj < 4; ++jj) {
                float d = y2[jj] - mean2;
                vr2 += d * d;
            }
            vr2 += __shfl_xor(vr2, 1, 64);  vr2 += __shfl_xor(vr2, 2, 64);
            vr2 += __shfl_xor(vr2, 4, 64);  vr2 += __shfl_xor(vr2, 8, 64);
            vr2 += __shfl_xor(vr2, 16, 64);
            float rstd2 = rsqrtf(vr2 * (1.0f / HH) + 1e-8f);
            int pid = pos_seqs[row];
            int nid = neg_seqs[row];
            float pp = 0.f, nn = 0.f;
#pragma unroll
            for (int jj = 0; jj < 4; ++jj) {
                int cc = cl + 32 * jj;
                float lf = (y2[jj] - mean2) * rstd2 * lnf_g[cc] + lnf_b[cc];
                pp += lf * item_emb[pid * HH + cc];
                nn += lf * item_emb[nid * HH + cc];
            }
            pp += __shfl_xor(pp, 1, 64);  pp += __shfl_xor(pp, 2, 64);
            pp += __shfl_xor(pp, 4, 64);  pp += __shfl_xor(pp, 8, 64);
            pp += __shfl_xor(pp, 16, 64);
            nn += __shfl_xor(nn, 1, 64);  nn += __shfl_xor(nn, 2, 64);
            nn += __shfl_xor(nn, 4, 64);  nn += __shfl_xor(nn, 8, 64);
            nn += __shfl_xor(nn, 16, 64);
            if (cl == 0) {
                out[row] = pp;
                out[BB * LL + row] = nn;
            }
        }
    }
}

extern "C" void kernel_launch(void* const* d_in, const int* in_sizes, int n_in,
                              void* d_out, int out_size, void* d_ws, size_t ws_size,
                              hipStream_t stream) {
    const int* log_seqs = (const int*)d_in[1];
    const int* tm       = (const int*)d_in[2];
    const int* pos_seqs = (const int*)d_in[3];
    const int* neg_seqs = (const int*)d_in[4];
    const float* item_emb = (const float*)d_in[5];
    const float* posK   = (const float*)d_in[6];
    const float* posV   = (const float*)d_in[7];
    const float* timeK  = (const float*)d_in[8];
    const float* timeV  = (const float*)d_in[9];
    const float* Wq = (const float*)d_in[10];
    const float* bq = (const float*)d_in[11];
    const float* Wk = (const float*)d_in[12];
    const float* bk = (const float*)d_in[13];
    const float* Wv = (const float*)d_in[14];
    const float* bv = (const float*)d_in[15];
    const float* ln1_g = (const float*)d_in[16];
    const float* ln1_b = (const float*)d_in[17];
    const float* W1 = (const float*)d_in[18];
    const float* b1 = (const float*)d_in[19];
    const float* W2 = (const float*)d_in[20];
    const float* b2 = (const float*)d_in[21];
    const float* ln2_g = (const float*)d_in[22];
    const float* ln2_b = (const float*)d_in[23];
    const float* lnf_g = (const float*)d_in[24];
    const float* lnf_b = (const float*)d_in[25];

    float* ws    = (float*)d_ws;
    float* seqs  = ws;                   // 409600 floats each
    float* Qb    = seqs + 409600;
    float* Kpb   = Qb + 409600;
    float* Vpb   = Kpb + 409600;
    float* AO    = Vpb + 409600;
    float* projK = AO + 409600;          // 32*200*257 = 1,644,800
    float* WT    = projK + 1644800;      // 10 * 16384 = 163,840

    // WT order: Wq0,Wq1,Wk0,Wk1,Wv0,Wv1,W10,W11,W20,W21
    k_prep<<<160, 256, 0, stream>>>(Wq, Wk, Wv, W1, W2, WT);

    for (int i = 0; i < 2; ++i) {
        const float* WTq = WT + (0 * 2 + i) * HH * HH;
        const float* WTk = WT + (1 * 2 + i) * HH * HH;
        const float* WTv = WT + (2 * 2 + i) * HH * HH;
        const float* WT1 = WT + (3 * 2 + i) * HH * HH;
        const float* WT2 = WT + (4 * 2 + i) * HH * HH;
        k_qkv<<<BB * LL / 8, 256, 0, stream>>>(seqs, log_seqs, item_emb,
            (i == 0) ? 1 : 0,
            WTq, bq + i * HH, WTk, bk + i * HH, WTv, bv + i * HH,
            posK, posV, Qb, Kpb, Vpb);
        k_proj<<<32 * NQT, 256, 0, stream>>>(Qb, timeK, projK);
        k_attn<<<32 * NQT, 256, 0, stream>>>(Qb, Kpb, Vpb, projK, timeV,
                                             tm, log_seqs, AO);
        k_ffn<<<BB * LL / 8, 256, 0, stream>>>(seqs, AO,
            ln1_g + i * HH, ln1_b + i * HH,
            WT1, b1 + i * HH, WT2, b2 + i * HH,
            ln2_g + i * HH, ln2_b + i * HH, log_seqs,
            (i == 1) ? 1 : 0, lnf_g, lnf_b, item_emb,
            pos_seqs, neg_seqs, (float*)d_out);
    }
}

// Round 15
// 187.460 us; speedup vs baseline: 3.5229x; 1.0393x over previous
//
#include <hip/hip_runtime.h>
#include <hip/hip_bf16.h>
#include <math.h>

#define BB 16
#define LL 200
#define HH 128
#define DD 64
#define NQT 25          // 200/8 q-tiles (proj)
#define NQT16 13        // ceil(200/16) q-tiles (attn)
#define NEGF -4294967295.0f
#define SQRTH 11.313708498984761f

// ---------------- QKV projection (16 rows/block, 512 threads), with embed (layer 0) ----------------
__global__ __launch_bounds__(512) void k_qkv(float* __restrict__ seqs,
    const int* __restrict__ log_seqs, const float* __restrict__ item_emb,
    const float* __restrict__ Wq, const float* __restrict__ bq,
    const float* __restrict__ Wk, const float* __restrict__ bk,
    const float* __restrict__ Wv, const float* __restrict__ bv,
    const float* __restrict__ posK, const float* __restrict__ posV,
    float* __restrict__ Q, float* __restrict__ Kp, float* __restrict__ Vp) {
    __shared__ float s_lds[16][HH];
    int r0g = blockIdx.x * 16;
    int t = threadIdx.x;
    {
        int r = t >> 5, d4 = t & 31;          // 16 rows x 32 float4
        int id = log_seqs[r0g + r];
        float4 v = make_float4(0.f, 0.f, 0.f, 0.f);
        if (id != 0) {
            v = ((const float4*)(item_emb + id * HH))[d4];
            v.x *= SQRTH; v.y *= SQRTH; v.z *= SQRTH; v.w *= SQRTH;
        }
        *(float4*)&s_lds[r][d4 * 4] = v;
        ((float4*)(seqs + r0g * HH))[t] = v;
    }
    __syncthreads();
    int c = t & 127, rg = t >> 7;
    float aq[4] = {0.f, 0.f, 0.f, 0.f};
    float ak[4] = {0.f, 0.f, 0.f, 0.f};
    float av[4] = {0.f, 0.f, 0.f, 0.f};
    const float4* wq4 = (const float4*)(Wq + c * HH);
    const float4* wk4 = (const float4*)(Wk + c * HH);
    const float4* wv4 = (const float4*)(Wv + c * HH);
#pragma unroll 4
    for (int k4 = 0; k4 < HH / 4; ++k4) {
        float4 wq = wq4[k4], wk = wk4[k4], wv = wv4[k4];
#pragma unroll
        for (int r = 0; r < 4; ++r) {
            float4 s = *(const float4*)&s_lds[rg * 4 + r][k4 * 4];
            aq[r] += s.x * wq.x + s.y * wq.y + s.z * wq.z + s.w * wq.w;
            ak[r] += s.x * wk.x + s.y * wk.y + s.z * wk.z + s.w * wk.w;
            av[r] += s.x * wv.x + s.y * wv.y + s.z * wv.z + s.w * wv.w;
        }
    }
#pragma unroll
    for (int r = 0; r < 4; ++r) {
        int row = r0g + rg * 4 + r;
        int l = row % LL;
        Q[row * HH + c]  = aq[r] + bq[c];
        Kp[row * HH + c] = ak[r] + bk[c] + posK[l * HH + c];
        Vp[row * HH + c] = av[r] + bv[c] + posV[l * HH + c];
    }
}

// ---------------- projK[bh,q,tt] = Q[b,q,h,:] . timeK[tt,h,:] ----------------
// grid = 32 bh * 25 qtiles(8); 256 threads: tq = t>>5, ttl = t&31
__global__ __launch_bounds__(256) void k_proj(const float* __restrict__ Q,
    const float* __restrict__ timeK, float* __restrict__ projK) {
    int bh = blockIdx.x / 25, qt = blockIdx.x % 25;
    int b = bh >> 1, h = bh & 1;
    int qlo = qt * 8;
    __shared__ float Qs[8][68];
    __shared__ float TK[32][68];
    int t = threadIdx.x;
    if (t < 128) {
        int r = t >> 4, d4 = t & 15;
        *(float4*)&Qs[r][d4 * 4] =
            ((const float4*)(Q + (b * LL + qlo + r) * HH + h * DD))[d4];
    }
    int tq = t >> 5, ttl = t & 31;
    for (int ch = 0; ch < 9; ++ch) {
        int base = ch * 32;
        __syncthreads();                 // protect TK (and Qs on ch==0)
        for (int x = t; x < 512; x += 256) {
            int i = x >> 4, d4 = x & 15;
            int tt = base + i;
            if (tt < 257)
                *(float4*)&TK[i][d4 * 4] =
                    ((const float4*)(timeK + tt * HH + h * DD))[d4];
        }
        __syncthreads();
        int tt = base + ttl;
        if (tt < 257) {
            float acc = 0.f;
#pragma unroll
            for (int d4 = 0; d4 < 16; ++d4) {
                float4 qv = *(const float4*)&Qs[tq][d4 * 4];
                float4 kv = *(const float4*)&TK[ttl][d4 * 4];
                acc += qv.x * kv.x + qv.y * kv.y + qv.z * kv.z + qv.w * kv.w;
            }
            projK[(bh * LL + qlo + tq) * 257 + tt] = acc;
        }
    }
}

// ---------------- fused scores + register-softmax + hist + PV, QT=16 ----------------
// grid = 32 bh * 13 qtiles(16); 512 threads: tq = t>>5 (q row), lane = t&31
// smemW stride 24 (16B-aligned rows): probs rows 0..199, hist rows 200..456, cols 0..15
__global__ __launch_bounds__(512) void k_attn(
    const float* __restrict__ Q, const float* __restrict__ Kp, const float* __restrict__ Vp,
    const float* __restrict__ projK, const float* __restrict__ timeV,
    const int* __restrict__ tm, const int* __restrict__ log_seqs,
    float* __restrict__ attnout) {
    int bh = blockIdx.x / NQT16, qt = blockIdx.x % NQT16;
    int b = bh >> 1, h = bh & 1;
    int qlo = qt * 16;
    __shared__ float K_s[32][68];            // 2176 floats
    __shared__ float smemW[457 * 24];        // 10968 floats
    __shared__ int s_allmask;
#define WT(i, j) smemW[(i) * 24 + (j)]
    int t = threadIdx.x;
    int tq = t >> 5, lane = t & 31;
    int q = qlo + tq;
    int qq = (q < LL) ? q : (LL - 1);        // tail rows clone row 199 (stores guarded)
    int qhi = qlo + 15; if (qhi > LL - 1) qhi = LL - 1;

    if (t == 0) s_allmask = 0;
    for (int x = 200 * 24 + t; x < 457 * 24; x += 512) smemW[x] = 0.f;
    float4 qreg[16];
    {
        const float4* qp = (const float4*)(Q + (b * LL + qq) * HH + h * DD);
#pragma unroll
        for (int d4 = 0; d4 < 16; ++d4) qreg[d4] = qp[d4];
    }
    const int* tmrow = tm + (b * LL + qq) * LL;
    const float* projrow = projK + (bh * LL + qq) * 257;
    const int* lsrow = log_seqs + b * LL;

    // phase 1: scores into registers s[7] (lane owns k = lane + 32*j)
    float s[7];
#pragma unroll
    for (int j = 0; j < 7; ++j) s[j] = NEGF;
    int nkc = (qhi >> 5) + 1;                // block-uniform, 1..7
#pragma unroll
    for (int kc = 0; kc < 7; ++kc) {
        if (kc < nkc) {
            int kbase = kc * 32;
            {
                int i = t >> 4, d4 = t & 15;   // 512 threads = 32 rows x 16 float4
                int k = kbase + i;
                if (k < LL)
                    *(float4*)&K_s[i][d4 * 4] =
                        ((const float4*)(Kp + (b * LL + k) * HH + h * DD))[d4];
            }
            __syncthreads();
            int k = kbase + lane;
            if (k <= qq && lsrow[k] != 0) {
                float acc = 0.f;
#pragma unroll
                for (int d4 = 0; d4 < 16; ++d4) {
                    float4 kv = *(const float4*)&K_s[lane][d4 * 4];
                    acc += qreg[d4].x * kv.x + qreg[d4].y * kv.y +
                           qreg[d4].z * kv.z + qreg[d4].w * kv.w;
                }
                s[kc] = (acc + projrow[tmrow[k]]) * 0.125f;
            }
            __syncthreads();
        }
    }

    // phase 2: softmax fully in registers (32 lanes per q row; xor<=16 stays in half-wave)
    float mx = s[0];
#pragma unroll
    for (int j = 1; j < 7; ++j) mx = fmaxf(mx, s[j]);
    mx = fmaxf(mx, __shfl_xor(mx, 1, 64));
    mx = fmaxf(mx, __shfl_xor(mx, 2, 64));
    mx = fmaxf(mx, __shfl_xor(mx, 4, 64));
    mx = fmaxf(mx, __shfl_xor(mx, 8, 64));
    mx = fmaxf(mx, __shfl_xor(mx, 16, 64));
    bool allmask = (mx == NEGF);             // exp(0)=1 per k -> uniform 1/200, matches ref
    float sum = 0.f;
#pragma unroll
    for (int j = 0; j < 7; ++j) {
        int k = lane + 32 * j;
        float e = (k < LL) ? __expf(s[j] - mx) : 0.f;
        s[j] = e;
        sum += e;
    }
    sum += __shfl_xor(sum, 1, 64);
    sum += __shfl_xor(sum, 2, 64);
    sum += __shfl_xor(sum, 4, 64);
    sum += __shfl_xor(sum, 8, 64);
    sum += __shfl_xor(sum, 16, 64);
    float inv = 1.0f / sum;
    int klim = allmask ? LL : (qq + 1);
    if (allmask && lane == 0) s_allmask = 1;
#pragma unroll
    for (int j = 0; j < 7; ++j) {
        int k = lane + 32 * j;
        if (k < LL) {
            float p = s[j] * inv;
            WT(k, tq) = p;
            if (k < klim && p != 0.f)
                atomicAdd(&WT(200 + tmrow[k], tq), p);
        }
    }
    __syncthreads();

    // phase 3: PV — 8 wave-groups stripe source rows; lane owns d-column l64,
    // 16 q accumulators; V row read 64x4B coalesced; weights 4x b128 broadcast.
    int g = t >> 6, l64 = t & 63;
    int kmax = s_allmask ? LL : (qhi + 1);
    float acc[16];
#pragma unroll
    for (int qi = 0; qi < 16; ++qi) acc[qi] = 0.f;
#define PV_STEP(WIDX, SRCPTR)                                            \
    {                                                                    \
        const float* wr = &WT(WIDX, 0);                                  \
        float4 w0 = *(const float4*)wr;                                  \
        float4 w1 = *(const float4*)(wr + 4);                            \
        float4 w2 = *(const float4*)(wr + 8);                            \
        float4 w3 = *(const float4*)(wr + 12);                           \
        float vv = *(SRCPTR);                                            \
        acc[0] += w0.x * vv;  acc[1] += w0.y * vv;                       \
        acc[2] += w0.z * vv;  acc[3] += w0.w * vv;                       \
        acc[4] += w1.x * vv;  acc[5] += w1.y * vv;                       \
        acc[6] += w1.z * vv;  acc[7] += w1.w * vv;                       \
        acc[8] += w2.x * vv;  acc[9] += w2.y * vv;                       \
        acc[10] += w2.z * vv; acc[11] += w2.w * vv;                      \
        acc[12] += w3.x * vv; acc[13] += w3.y * vv;                      \
        acc[14] += w3.z * vv; acc[15] += w3.w * vv;                      \
    }
    for (int i = g; i < kmax; i += 8)
        PV_STEP(i, Vp + (b * LL + i) * HH + h * DD + l64);
    for (int i = g; i < 257; i += 8)
        PV_STEP(200 + i, timeV + i * HH + h * DD + l64);
#undef PV_STEP
    __syncthreads();
    // partial reduce: part[g][qi][d] aliased onto smemW (8*16*64 = 8192 <= 10968)
    float* part = smemW;
#pragma unroll
    for (int qi = 0; qi < 16; ++qi)
        part[g * 1024 + qi * 64 + l64] = acc[qi];
    __syncthreads();
    {
#pragma unroll
        for (int rep = 0; rep < 2; ++rep) {
            int idx = t + rep * 512;           // 1024 outputs
            int q16 = idx >> 6, d = idx & 63;
            float ox = 0.f;
#pragma unroll
            for (int gg = 0; gg < 8; ++gg) ox += part[gg * 1024 + idx];
            if (qlo + q16 < LL)
                attnout[(b * LL + qlo + q16) * HH + h * DD + d] = ox;
        }
    }
#undef WT
}

// ---------------- fused: s1=LN1(seqs+AO); x2=s1+FFN(s1); y2=LN2(x2)*keep
//    do_qkv: also compute next layer's Q/Kp/Vp from y2 (and write seqs=y2)
//    do_final: lnf LayerNorm + pos/neg logits instead of seqs write ----------------
__global__ __launch_bounds__(512) void k_ffn_full(
    float* __restrict__ seqs, const float* __restrict__ AO,
    const float* __restrict__ g1, const float* __restrict__ be1,
    const float* __restrict__ W1, const float* __restrict__ b1,
    const float* __restrict__ W2, const float* __restrict__ b2,
    const float* __restrict__ g2, const float* __restrict__ be2,
    const int* __restrict__ log_seqs,
    int do_qkv,
    const float* __restrict__ Wq, const float* __restrict__ bq,
    const float* __restrict__ Wk, const float* __restrict__ bk,
    const float* __restrict__ Wv, const float* __restrict__ bv,
    const float* __restrict__ posK, const float* __restrict__ posV,
    float* __restrict__ Q, float* __restrict__ Kp, float* __restrict__ Vp,
    int do_final,
    const float* __restrict__ lnf_g, const float* __restrict__ lnf_b,
    const float* __restrict__ item_emb,
    const int* __restrict__ pos_seqs, const int* __restrict__ neg_seqs,
    float* __restrict__ out) {
    __shared__ float s_lds[16][HH];
    __shared__ float h_lds[16][HH];
    int r0g = blockIdx.x * 16;
    int t = threadIdx.x;
    {
        float4 a = ((const float4*)(seqs + r0g * HH))[t];
        float4 o = ((const float4*)(AO + r0g * HH))[t];
        a.x += o.x; a.y += o.y; a.z += o.z; a.w += o.w;
        ((float4*)s_lds)[t] = a;
    }
    __syncthreads();
    int w = t >> 6, lane = t & 63;
    int lrow = w * 2 + (lane >> 5), cl = lane & 31;
    // LN1 in-place
    {
        float sm = 0.f;
#pragma unroll
        for (int j = 0; j < 4; ++j) sm += s_lds[lrow][cl + 32 * j];
        sm += __shfl_xor(sm, 1, 64);  sm += __shfl_xor(sm, 2, 64);
        sm += __shfl_xor(sm, 4, 64);  sm += __shfl_xor(sm, 8, 64);
        sm += __shfl_xor(sm, 16, 64);
        float mean = sm * (1.0f / HH);
        float vr = 0.f;
#pragma unroll
        for (int j = 0; j < 4; ++j) {
            float d = s_lds[lrow][cl + 32 * j] - mean;
            vr += d * d;
        }
        vr += __shfl_xor(vr, 1, 64);  vr += __shfl_xor(vr, 2, 64);
        vr += __shfl_xor(vr, 4, 64);  vr += __shfl_xor(vr, 8, 64);
        vr += __shfl_xor(vr, 16, 64);
        float rstd = rsqrtf(vr * (1.0f / HH) + 1e-8f);
#pragma unroll
        for (int j = 0; j < 4; ++j) {
            int c = cl + 32 * j;
            s_lds[lrow][c] = (s_lds[lrow][c] - mean) * rstd * g1[c] + be1[c];
        }
    }
    __syncthreads();
    // GEMM1 + relu
    int c = t & 127, rg = t >> 7;
    float acc[4] = {0.f, 0.f, 0.f, 0.f};
    const float4* w14 = (const float4*)(W1 + c * HH);
#pragma unroll 4
    for (int k4 = 0; k4 < HH / 4; ++k4) {
        float4 ww = w14[k4];
#pragma unroll
        for (int r = 0; r < 4; ++r) {
            float4 s = *(const float4*)&s_lds[rg * 4 + r][k4 * 4];
            acc[r] += s.x * ww.x + s.y * ww.y + s.z * ww.z + s.w * ww.w;
        }
    }
#pragma unroll
    for (int r = 0; r < 4; ++r) h_lds[rg * 4 + r][c] = fmaxf(acc[r] + b1[c], 0.f);
    __syncthreads();
    // GEMM2
#pragma unroll
    for (int r = 0; r < 4; ++r) acc[r] = 0.f;
    const float4* w24 = (const float4*)(W2 + c * HH);
#pragma unroll 4
    for (int k4 = 0; k4 < HH / 4; ++k4) {
        float4 ww = w24[k4];
#pragma unroll
        for (int r = 0; r < 4; ++r) {
            float4 s = *(const float4*)&h_lds[rg * 4 + r][k4 * 4];
            acc[r] += s.x * ww.x + s.y * ww.y + s.z * ww.z + s.w * ww.w;
        }
    }
    __syncthreads();
#pragma unroll
    for (int r = 0; r < 4; ++r)
        h_lds[rg * 4 + r][c] = s_lds[rg * 4 + r][c] + acc[r] + b2[c];
    __syncthreads();
    // LN2 + keep
    {
        float sm = 0.f;
#pragma unroll
        for (int j = 0; j < 4; ++j) sm += h_lds[lrow][cl + 32 * j];
        sm += __shfl_xor(sm, 1, 64);  sm += __shfl_xor(sm, 2, 64);
        sm += __shfl_xor(sm, 4, 64);  sm += __shfl_xor(sm, 8, 64);
        sm += __shfl_xor(sm, 16, 64);
        float mean = sm * (1.0f / HH);
        float vr = 0.f;
#pragma unroll
        for (int j = 0; j < 4; ++j) {
            float d = h_lds[lrow][cl + 32 * j] - mean;
            vr += d * d;
        }
        vr += __shfl_xor(vr, 1, 64);  vr += __shfl_xor(vr, 2, 64);
        vr += __shfl_xor(vr, 4, 64);  vr += __shfl_xor(vr, 8, 64);
        vr += __shfl_xor(vr, 16, 64);
        float rstd = rsqrtf(vr * (1.0f / HH) + 1e-8f);
        int row = r0g + lrow;
        float keep = (log_seqs[row] != 0) ? 1.0f : 0.0f;
        float y2[4];
#pragma unroll
        for (int j = 0; j < 4; ++j) {
            int cc = cl + 32 * j;
            y2[j] = ((h_lds[lrow][cc] - mean) * rstd * g2[cc] + be2[cc]) * keep;
        }
        if (do_final) {
            float sm2 = y2[0] + y2[1] + y2[2] + y2[3];
            sm2 += __shfl_xor(sm2, 1, 64);  sm2 += __shfl_xor(sm2, 2, 64);
            sm2 += __shfl_xor(sm2, 4, 64);  sm2 += __shfl_xor(sm2, 8, 64);
            sm2 += __shfl_xor(sm2, 16, 64);
            float mean2 = sm2 * (1.0f / HH);
            float vr2 = 0.f;
#pragma unroll
            for (int j = 0; j < 4; ++j) {
                float d = y2[j] - mean2;
                vr2 += d * d;
            }
            vr2 += __shfl_xor(vr2, 1, 64);  vr2 += __shfl_xor(vr2, 2, 64);
            vr2 += __shfl_xor(vr2, 4, 64);  vr2 += __shfl_xor(vr2, 8, 64);
            vr2 += __shfl_xor(vr2, 16, 64);
            float rstd2 = rsqrtf(vr2 * (1.0f / HH) + 1e-8f);
            int pid = pos_seqs[row];
            int nid = neg_seqs[row];
            float pp = 0.f, nn = 0.f;
#pragma unroll
            for (int j = 0; j < 4; ++j) {
                int cc = cl + 32 * j;
                float lf = (y2[j] - mean2) * rstd2 * lnf_g[cc] + lnf_b[cc];
                pp += lf * item_emb[pid * HH + cc];
                nn += lf * item_emb[nid * HH + cc];
            }
            pp += __shfl_xor(pp, 1, 64);  pp += __shfl_xor(pp, 2, 64);
            pp += __shfl_xor(pp, 4, 64);  pp += __shfl_xor(pp, 8, 64);
            pp += __shfl_xor(pp, 16, 64);
            nn += __shfl_xor(nn, 1, 64);  nn += __shfl_xor(nn, 2, 64);
            nn += __shfl_xor(nn, 4, 64);  nn += __shfl_xor(nn, 8, 64);
            nn += __shfl_xor(nn, 16, 64);
            if (cl == 0) {
                out[row] = pp;
                out[BB * LL + row] = nn;
            }
        } else {
#pragma unroll
            for (int j = 0; j < 4; ++j)
                seqs[row * HH + cl + 32 * j] = y2[j];
            if (do_qkv) {
#pragma unroll
                for (int j = 0; j < 4; ++j)
                    s_lds[lrow][cl + 32 * j] = y2[j];   // park y2 for QKV
            }
        }
    }
    if (!do_qkv) return;
    __syncthreads();
    // next-layer QKV from y2 in s_lds
    float aq[4] = {0.f, 0.f, 0.f, 0.f};
    float ak[4] = {0.f, 0.f, 0.f, 0.f};
    float av[4] = {0.f, 0.f, 0.f, 0.f};
    const float4* wq4 = (const float4*)(Wq + c * HH);
    const float4* wk4 = (const float4*)(Wk + c * HH);
    const float4* wv4 = (const float4*)(Wv + c * HH);
#pragma unroll 4
    for (int k4 = 0; k4 < HH / 4; ++k4) {
        float4 wq = wq4[k4], wk = wk4[k4], wv = wv4[k4];
#pragma unroll
        for (int r = 0; r < 4; ++r) {
            float4 s = *(const float4*)&s_lds[rg * 4 + r][k4 * 4];
            aq[r] += s.x * wq.x + s.y * wq.y + s.z * wq.z + s.w * wq.w;
            ak[r] += s.x * wk.x + s.y * wk.y + s.z * wk.z + s.w * wk.w;
            av[r] += s.x * wv.x + s.y * wv.y + s.z * wv.z + s.w * wv.w;
        }
    }
#pragma unroll
    for (int r = 0; r < 4; ++r) {
        int row = r0g + rg * 4 + r;
        int l = row % LL;
        Q[row * HH + c]  = aq[r] + bq[c];
        Kp[row * HH + c] = ak[r] + bk[c] + posK[l * HH + c];
        Vp[row * HH + c] = av[r] + bv[c] + posV[l * HH + c];
    }
}

extern "C" void kernel_launch(void* const* d_in, const int* in_sizes, int n_in,
                              void* d_out, int out_size, void* d_ws, size_t ws_size,
                              hipStream_t stream) {
    const int* log_seqs = (const int*)d_in[1];
    const int* tm       = (const int*)d_in[2];
    const int* pos_seqs = (const int*)d_in[3];
    const int* neg_seqs = (const int*)d_in[4];
    const float* item_emb = (const float*)d_in[5];
    const float* posK   = (const float*)d_in[6];
    const float* posV   = (const float*)d_in[7];
    const float* timeK  = (const float*)d_in[8];
    const float* timeV  = (const float*)d_in[9];
    const float* Wq = (const float*)d_in[10];
    const float* bq = (const float*)d_in[11];
    const float* Wk = (const float*)d_in[12];
    const float* bk = (const float*)d_in[13];
    const float* Wv = (const float*)d_in[14];
    const float* bv = (const float*)d_in[15];
    const float* ln1_g = (const float*)d_in[16];
    const float* ln1_b = (const float*)d_in[17];
    const float* W1 = (const float*)d_in[18];
    const float* b1 = (const float*)d_in[19];
    const float* W2 = (const float*)d_in[20];
    const float* b2 = (const float*)d_in[21];
    const float* ln2_g = (const float*)d_in[22];
    const float* ln2_b = (const float*)d_in[23];
    const float* lnf_g = (const float*)d_in[24];
    const float* lnf_b = (const float*)d_in[25];

    float* ws    = (float*)d_ws;
    float* seqs  = ws;                   // 409600 floats each
    float* Qb    = seqs + 409600;
    float* Kpb   = Qb + 409600;
    float* Vpb   = Kpb + 409600;
    float* AO    = Vpb + 409600;
    float* projK = AO + 409600;          // 32*200*257 = 1,644,800

    // layer 0
    k_qkv<<<BB * LL / 16, 512, 0, stream>>>(seqs, log_seqs, item_emb,
        Wq, bq, Wk, bk, Wv, bv, posK, posV, Qb, Kpb, Vpb);
    k_proj<<<32 * NQT, 256, 0, stream>>>(Qb, timeK, projK);
    k_attn<<<32 * NQT16, 512, 0, stream>>>(Qb, Kpb, Vpb, projK, timeV,
                                           tm, log_seqs, AO);
    // layer-0 FFN fused with layer-1 QKV
    k_ffn_full<<<BB * LL / 16, 512, 0, stream>>>(seqs, AO,
        ln1_g, ln1_b, W1, b1, W2, b2, ln2_g, ln2_b, log_seqs,
        1, Wq + HH * HH, bq + HH, Wk + HH * HH, bk + HH, Wv + HH * HH, bv + HH,
        posK, posV, Qb, Kpb, Vpb,
        0, lnf_g, lnf_b, item_emb, pos_seqs, neg_seqs, (float*)d_out);
    // layer 1
    k_proj<<<32 * NQT, 256, 0, stream>>>(Qb, timeK, projK);
    k_attn<<<32 * NQT16, 512, 0, stream>>>(Qb, Kpb, Vpb, projK, timeV,
                                           tm, log_seqs, AO);
    k_ffn_full<<<BB * LL / 16, 512, 0, stream>>>(seqs, AO,
        ln1_g + HH, ln1_b + HH, W1 + HH * HH, b1 + HH, W2 + HH * HH, b2 + HH,
        ln2_g + HH, ln2_b + HH, log_seqs,
        0, nullptr, nullptr, nullptr, nullptr, nullptr, nullptr,
        nullptr, nullptr, nullptr, nullptr, nullptr,
        1, lnf_g, lnf_b, item_emb, pos_seqs, neg_seqs, (float*)d_out);
}